// Round 1
// baseline (209.555 us; speedup 1.0000x reference)
//
#include <hip/hip_runtime.h>
#include <hip/hip_bf16.h>

#define BDIM 4
#define NSEQ 4096
#define DHEAD 128
#define SCALE 0.08838834764831845f

typedef __bf16 bf16x8 __attribute__((ext_vector_type(8)));
typedef float f32x4 __attribute__((ext_vector_type(4)));

__device__ __forceinline__ unsigned short f2bf(float f){
    return __builtin_bit_cast(unsigned short, (__bf16)f);
}

// ---------------------------------------------------------------------------
// Kernel 1: per-row softmax stats (m, l) with K-split=4.
// grid = B(4) * rowtiles(64) * ksplit(4) = 1024 blocks, 256 threads (4 waves).
// Each wave owns 16 query rows; block covers 64 rows x 1024 key cols.
// Partials (m,l) per split are written into attn output cols [2*ks, 2*ks+1].
// ---------------------------------------------------------------------------
extern "C" __global__ __launch_bounds__(256, 4)
void attn_stats(const float* __restrict__ K, const float* __restrict__ Q,
                float* __restrict__ out)
{
    __shared__ __align__(16) char Klds[64 * 256];   // 64 rows x 128 bf16 (swizzled)

    const int bid = blockIdx.x;
    const int ks  = bid & 3;
    const int rt  = (bid >> 2) & 63;
    const int b   = bid >> 8;
    const int tid = threadIdx.x;
    const int lane = tid & 63;
    const int w    = tid >> 6;
    const int g    = lane >> 4;
    const int c    = lane & 15;
    const int rowbase = rt * 64;

    // ---- Q fragments (A-operand), scale folded in ----
    const float* qrow = Q + ((size_t)b * NSEQ + rowbase + w * 16 + c) * DHEAD;
    bf16x8 qf[4];
#pragma unroll
    for (int kk = 0; kk < 4; kk++) {
        const float4* p0 = (const float4*)(qrow + g * 8 + kk * 32);
        float4 u = p0[0], v = p0[1];
        bf16x8 t;
        t[0] = (__bf16)(u.x * SCALE); t[1] = (__bf16)(u.y * SCALE);
        t[2] = (__bf16)(u.z * SCALE); t[3] = (__bf16)(u.w * SCALE);
        t[4] = (__bf16)(v.x * SCALE); t[5] = (__bf16)(v.y * SCALE);
        t[6] = (__bf16)(v.z * SCALE); t[7] = (__bf16)(v.w * SCALE);
        qf[kk] = t;
    }

    float m[4], l[4];
#pragma unroll
    for (int r = 0; r < 4; r++) { m[r] = -1e30f; l[r] = 0.0f; }

    const int f  = tid & 31;    // float4 index within a 128-float row
    const int r0 = tid >> 5;    // 0..7

    for (int kt = 0; kt < 16; kt++) {
        const float* ktile = K + ((size_t)b * NSEQ + ks * 1024 + kt * 64) * DHEAD;
        // ---- stage K tile (64x128) fp32 -> bf16 LDS, XOR-swizzled ----
#pragma unroll
        for (int i = 0; i < 8; i++) {
            int r = r0 + i * 8;
            float4 u = *(const float4*)(ktile + (size_t)r * DHEAD + f * 4);
            unsigned long long pk =
                (unsigned long long)f2bf(u.x)
              | ((unsigned long long)f2bf(u.y) << 16)
              | ((unsigned long long)f2bf(u.z) << 32)
              | ((unsigned long long)f2bf(u.w) << 48);
            *(unsigned long long*)(Klds + r * 256 + ((f * 8) ^ ((r & 7) << 4))) = pk;
        }
        __syncthreads();

        // ---- S = Q K^T (16x64 per wave) ----
        f32x4 acc[4];
#pragma unroll
        for (int n = 0; n < 4; n++) acc[n] = (f32x4){0.f, 0.f, 0.f, 0.f};
#pragma unroll
        for (int n = 0; n < 4; n++) {
            int row = n * 16 + c;
#pragma unroll
            for (int kk = 0; kk < 4; kk++) {
                bf16x8 kf = *(const bf16x8*)(Klds + row * 256 +
                                ((g * 16 + kk * 64) ^ ((row & 7) << 4)));
                acc[n] = __builtin_amdgcn_mfma_f32_16x16x32_bf16(qf[kk], kf, acc[n], 0, 0, 0);
            }
        }

        // ---- online stats update ----
#pragma unroll
        for (int r = 0; r < 4; r++) {
            float t = fmaxf(fmaxf(acc[0][r], acc[1][r]), fmaxf(acc[2][r], acc[3][r]));
            t = fmaxf(t, __shfl_xor(t, 1));
            t = fmaxf(t, __shfl_xor(t, 2));
            t = fmaxf(t, __shfl_xor(t, 4));
            t = fmaxf(t, __shfl_xor(t, 8));
            float mn = fmaxf(m[r], t);
            float sc = __expf(m[r] - mn);
            float ps = __expf(acc[0][r] - mn) + __expf(acc[1][r] - mn)
                     + __expf(acc[2][r] - mn) + __expf(acc[3][r] - mn);
            ps += __shfl_xor(ps, 1);
            ps += __shfl_xor(ps, 2);
            ps += __shfl_xor(ps, 4);
            ps += __shfl_xor(ps, 8);
            l[r] = l[r] * sc + ps;
            m[r] = mn;
        }
        __syncthreads();
    }

    // ---- write partials into attn cols [2ks, 2ks+1] ----
    if (c == 0) {
        float* attn = out + (size_t)BDIM * NSEQ * DHEAD;
#pragma unroll
        for (int r = 0; r < 4; r++) {
            size_t row = rowbase + w * 16 + g * 4 + r;
            float* p = attn + ((size_t)b * NSEQ + row) * NSEQ + ks * 2;
            p[0] = m[r];
            p[1] = l[r];
        }
    }
}

// ---------------------------------------------------------------------------
// Kernel 2: finalize. Combine partials -> C = m + log(l); recompute S, write
// P = exp(s - C) to attn, accumulate context = P V.
// grid = B(4) * rowtiles(64) = 256 blocks, 512 threads (8 waves).
// Wave w: rows (w&3)*16, column-half (w>>2) (2048 cols = 32 tiles of 64).
// ---------------------------------------------------------------------------
extern "C" __global__ __launch_bounds__(512, 2)
void attn_final(const float* __restrict__ K, const float* __restrict__ Q,
                const float* __restrict__ V, float* __restrict__ out)
{
    __shared__ __align__(16) char KldsA[2][64 * 256];    // 2 x 16 KB
    __shared__ __align__(16) char VtldsA[2][128 * 128];  // 2 x 16 KB (Vt: 128 rows x 64 bf16)
    __shared__ __align__(16) char PldsA[8][16 * 128];    // 8 x 2 KB  (16 rows x 64 bf16)
    __shared__ float Crow[64];

    const int bid = blockIdx.x;
    const int rt  = bid & 63;
    const int b   = bid >> 6;
    const int tid = threadIdx.x;
    const int rowbase = rt * 64;

    float* ctxOut = out;
    float* attn   = out + (size_t)BDIM * NSEQ * DHEAD;

    // ---- prologue: combine the 4 K-split partials -> C = M + log(L) ----
    if (tid < 64) {
        const float* p = attn + ((size_t)b * NSEQ + rowbase + tid) * NSEQ;
        float m0 = p[0], l0 = p[1], m1 = p[2], l1 = p[3];
        float m2 = p[4], l2 = p[5], m3 = p[6], l3 = p[7];
        float M = fmaxf(fmaxf(m0, m1), fmaxf(m2, m3));
        float L = l0 * __expf(m0 - M) + l1 * __expf(m1 - M)
                + l2 * __expf(m2 - M) + l3 * __expf(m3 - M);
        Crow[tid] = M + __logf(L);
    }
    __syncthreads();

    const int lane = tid & 63;
    const int w    = tid >> 6;
    const int rw   = w & 3;
    const int grp  = w >> 2;
    const int gt   = tid & 255;
    const int g    = lane >> 4;
    const int c    = lane & 15;

    char* Klds  = KldsA[grp];
    char* Vtlds = VtldsA[grp];
    char* Plds  = PldsA[w];

    // ---- Q fragments ----
    const float* qrow = Q + ((size_t)b * NSEQ + rowbase + rw * 16 + c) * DHEAD;
    bf16x8 qf[4];
#pragma unroll
    for (int kk = 0; kk < 4; kk++) {
        const float4* p0 = (const float4*)(qrow + g * 8 + kk * 32);
        float4 u = p0[0], v = p0[1];
        bf16x8 t;
        t[0] = (__bf16)(u.x * SCALE); t[1] = (__bf16)(u.y * SCALE);
        t[2] = (__bf16)(u.z * SCALE); t[3] = (__bf16)(u.w * SCALE);
        t[4] = (__bf16)(v.x * SCALE); t[5] = (__bf16)(v.y * SCALE);
        t[6] = (__bf16)(v.z * SCALE); t[7] = (__bf16)(v.w * SCALE);
        qf[kk] = t;
    }

    float Cst[4];
#pragma unroll
    for (int r = 0; r < 4; r++) Cst[r] = Crow[rw * 16 + g * 4 + r];

    f32x4 ctx[8];
#pragma unroll
    for (int n2 = 0; n2 < 8; n2++) ctx[n2] = (f32x4){0.f, 0.f, 0.f, 0.f};

    const int f  = gt & 31;
    const int r0 = gt >> 5;

    for (int kt = 0; kt < 32; kt++) {
        const int col0 = grp * 2048 + kt * 64;
        const float* ktile = K + ((size_t)b * NSEQ + col0) * DHEAD;
        const float* vtile = V + ((size_t)b * NSEQ + col0) * DHEAD;

        // ---- stage K (row-major bf16, swizzled) ----
#pragma unroll
        for (int i = 0; i < 8; i++) {
            int r = r0 + i * 8;
            float4 u = *(const float4*)(ktile + (size_t)r * DHEAD + f * 4);
            unsigned long long pk =
                (unsigned long long)f2bf(u.x)
              | ((unsigned long long)f2bf(u.y) << 16)
              | ((unsigned long long)f2bf(u.z) << 32)
              | ((unsigned long long)f2bf(u.w) << 48);
            *(unsigned long long*)(Klds + r * 256 + ((f * 8) ^ ((r & 7) << 4))) = pk;
        }
        // ---- stage V transposed (Vt[d][k], bf16, swizzled) ----
#pragma unroll
        for (int i = 0; i < 4; i++) {
            int tt = gt + 256 * i;
            int pr = tt >> 5;          // key-row pair 0..31
            int fv = tt & 31;          // float4 idx in d
            int k2 = pr * 2;
            float4 a  = *(const float4*)(vtile + (size_t)k2 * DHEAD + fv * 4);
            float4 bb = *(const float4*)(vtile + (size_t)(k2 + 1) * DHEAD + fv * 4);
#pragma unroll
            for (int j = 0; j < 4; j++) {
                int d = fv * 4 + j;
                float va = ((const float*)&a)[j];
                float vb = ((const float*)&bb)[j];
                unsigned int pk = (unsigned int)f2bf(va) | ((unsigned int)f2bf(vb) << 16);
                *(unsigned int*)(Vtlds + d * 128 + ((k2 * 2) ^ ((d & 7) << 4))) = pk;
            }
        }
        __syncthreads();

        // ---- S = Q K^T ----
        f32x4 sacc[4];
#pragma unroll
        for (int n = 0; n < 4; n++) sacc[n] = (f32x4){0.f, 0.f, 0.f, 0.f};
#pragma unroll
        for (int n = 0; n < 4; n++) {
            int row = n * 16 + c;
#pragma unroll
            for (int kk = 0; kk < 4; kk++) {
                bf16x8 kf = *(const bf16x8*)(Klds + row * 256 +
                                ((g * 16 + kk * 64) ^ ((row & 7) << 4)));
                sacc[n] = __builtin_amdgcn_mfma_f32_16x16x32_bf16(qf[kk], kf, sacc[n], 0, 0, 0);
            }
        }

        // ---- P = exp(s - C); store attn; stash bf16 P in LDS ----
        float pv[4][4];
#pragma unroll
        for (int n = 0; n < 4; n++)
#pragma unroll
            for (int r = 0; r < 4; r++)
                pv[n][r] = __expf(sacc[n][r] - Cst[r]);

#pragma unroll
        for (int r = 0; r < 4; r++) {
            float* arow = attn + ((size_t)b * NSEQ + rowbase + rw * 16 + g * 4 + r) * NSEQ
                        + col0 + c;
#pragma unroll
            for (int n = 0; n < 4; n++) arow[n * 16] = pv[n][r];
        }

#pragma unroll
        for (int n = 0; n < 4; n++)
#pragma unroll
            for (int r = 0; r < 4; r++) {
                int row = g * 4 + r;
                *(unsigned short*)(Plds + row * 128 +
                    ((n * 32 + c * 2) ^ ((row & 7) << 4))) = f2bf(pv[n][r]);
            }
        asm volatile("s_waitcnt lgkmcnt(0)" ::: "memory");

        bf16x8 pf[2];
#pragma unroll
        for (int kk = 0; kk < 2; kk++)
            pf[kk] = *(const bf16x8*)(Plds + c * 128 +
                        ((g * 16 + kk * 64) ^ ((c & 7) << 4)));

        // ---- context += P V ----
#pragma unroll
        for (int n2 = 0; n2 < 8; n2++) {
#pragma unroll
            for (int kk = 0; kk < 2; kk++) {
                int row = n2 * 16 + c;
                bf16x8 vf = *(const bf16x8*)(Vtlds + row * 128 +
                                ((g * 16 + kk * 64) ^ ((row & 7) << 4)));
                ctx[n2] = __builtin_amdgcn_mfma_f32_16x16x32_bf16(pf[kk], vf, ctx[n2], 0, 0, 0);
            }
        }
        __syncthreads();
    }

    // ---- reduce context across the two column-groups, store ----
    float* red = (float*)&KldsA[0][0];   // 64 x 128 fp32 = 32 KB overlay
    if (grp == 1) {
#pragma unroll
        for (int n2 = 0; n2 < 8; n2++)
#pragma unroll
            for (int r = 0; r < 4; r++)
                red[(rw * 16 + g * 4 + r) * 128 + n2 * 16 + c] = ctx[n2][r];
    }
    __syncthreads();
    if (grp == 0) {
#pragma unroll
        for (int n2 = 0; n2 < 8; n2++)
#pragma unroll
            for (int r = 0; r < 4; r++) {
                size_t row = rowbase + rw * 16 + g * 4 + r;
                ctxOut[((size_t)b * NSEQ + row) * DHEAD + n2 * 16 + c] =
                    ctx[n2][r] + red[(rw * 16 + g * 4 + r) * 128 + n2 * 16 + c];
            }
    }
}

extern "C" void kernel_launch(void* const* d_in, const int* in_sizes, int n_in,
                              void* d_out, int out_size, void* d_ws, size_t ws_size,
                              hipStream_t stream)
{
    const float* K = (const float*)d_in[0];   // "key"
    const float* Q = (const float*)d_in[1];   // "query"
    const float* V = (const float*)d_in[2];   // "value"
    float* out = (float*)d_out;

    attn_stats<<<dim3(4 * 64 * 4), dim3(256), 0, stream>>>(K, Q, out);
    attn_final<<<dim3(4 * 64), dim3(512), 0, stream>>>(K, Q, V, out);
}